// Round 6
// baseline (145.394 us; speedup 1.0000x reference)
//
#include <hip/hip_runtime.h>
#include <stdint.h>

#define NROWS 32768
#define DIMS  256
#define KCB   1024

typedef _Float16 half8   __attribute__((ext_vector_type(8)));
typedef float    f32x4   __attribute__((ext_vector_type(4)));
typedef short    short4v __attribute__((ext_vector_type(4)));
typedef short    short8v __attribute__((ext_vector_type(8)));

__device__ __forceinline__ short2 f16split(float v) {
    _Float16 hh = (_Float16)v;
    _Float16 ll = (_Float16)(v - (float)hh);
    return make_short2(__builtin_bit_cast(short, hh),
                       __builtin_bit_cast(short, ll));
}

// ---- E -> fragment-ordered f16 h/l planes + he2 (verified round 5) -------
// Ep frag-pair (G=code-group of 16, cc=k-chunk of 32) is 2KB:
//   h-plane at G*16384 + cc*2048 + lane*16 bytes, l-plane +1024.
__global__ __launch_bounds__(256) void esplit(const float* __restrict__ embed,
                                              short* __restrict__ Ep,
                                              float* __restrict__ he2) {
    int r = blockIdx.x * 4 + (threadIdx.x >> 6);   // code row 0..1023
    int l = threadIdx.x & 63;
    f32x4 v = ((const f32x4*)(embed + (size_t)r * DIMS))[l];
    float s = v[0]*v[0] + v[1]*v[1] + v[2]*v[2] + v[3]*v[3];
    #pragma unroll
    for (int off = 32; off > 0; off >>= 1) s += __shfl_down(s, off, 64);
    if (l == 0) he2[r] = 0.5f * s;
    int G = r >> 4, cc = l >> 3;
    int fl = (r & 15) + 16 * ((l >> 1) & 3);
    size_t base = (size_t)G * 8192 + cc * 1024 + fl * 8 + (l & 1) * 4;
    short4v h, lo;
    #pragma unroll
    for (int e = 0; e < 4; ++e) { short2 q = f16split(v[e]); h[e] = q.x; lo[e] = q.y; }
    *(short4v*)(Ep + base)       = h;
    *(short4v*)(Ep + base + 512) = lo;
}

// ---- main: 64 rows x 1024 codes per block, full K, barrier-free loop -----
// LDS A: frag(m=0..3, c=0..7) pair = 2KB at (m*8+c)*2048; h at +0, l at +1024;
// within plane lane-linear (lane*16 bytes) -> conflict-free ds_read_b128.
__global__ __launch_bounds__(256, 2) void vq_full(
    const float* __restrict__ x, const short* __restrict__ Ep,
    const float* __restrict__ embed, const float* __restrict__ he2,
    float* __restrict__ outq, float* __restrict__ outi)
{
    __shared__ short A[32 * 1024];        // 64 KB
    __shared__ float sarr[64 * 4];
    __shared__ int   iarr[64 * 4];
    __shared__ int   idxS[64];

    const int t = threadIdx.x, lane = t & 63, w = t >> 6;
    const int rowBase = blockIdx.x * 64;

    // ---- prologue: stage this block's X rows as f16 h/l fragments --------
    // wave w owns m-frag w: rows rowBase + w*16 + (lane&15), all 8 k-chunks
    {
        const int row = rowBase + w * 16 + (lane & 15);
        const float* xr = x + (size_t)row * DIMS + (lane >> 4) * 8;
        #pragma unroll
        for (int c = 0; c < 8; ++c) {
            f32x4 a = *(const f32x4*)(xr + c * 32);
            f32x4 b = *(const f32x4*)(xr + c * 32 + 4);
            short8v h, lo;
            #pragma unroll
            for (int e = 0; e < 4; ++e) { short2 q = f16split(a[e]); h[e] = q.x; lo[e] = q.y; }
            #pragma unroll
            for (int e = 0; e < 4; ++e) { short2 q = f16split(b[e]); h[4+e] = q.x; lo[4+e] = q.y; }
            int base = ((w * 8 + c) * 1024 + lane * 8);        // shorts
            *(short8v*)(A + base)       = h;
            *(short8v*)(A + base + 512) = lo;
        }
    }
    __syncthreads();

    // ---- main loop: wave w covers cols w*256 .. w*256+255 ----------------
    const int colBase = w * 256;
    const char* EpB = (const char*)Ep + (size_t)(colBase >> 4) * 16384 + lane * 16;
    const short* Ash = A + lane * 8;

    float best[16];
    int   bidx[16];
    #pragma unroll
    for (int s = 0; s < 16; ++s) { best[s] = -3.4e38f; bidx[s] = 0; }

    #pragma unroll 1
    for (int g = 0; g < 4; ++g) {                 // 4 n-groups of 64 cols
        f32x4 acc[4][4];
        #pragma unroll
        for (int m = 0; m < 4; ++m)
            #pragma unroll
            for (int n = 0; n < 4; ++n) acc[m][n] = (f32x4){0.f, 0.f, 0.f, 0.f};

        const char* EpG = EpB + (size_t)g * 4 * 16384;
        #pragma unroll
        for (int c = 0; c < 8; ++c) {
            half8 Ah[4], Al[4], Bh[4], Bl[4];
            #pragma unroll
            for (int m = 0; m < 4; ++m) {
                Ah[m] = *(const half8*)(Ash + (m * 8 + c) * 1024);
                Al[m] = *(const half8*)(Ash + (m * 8 + c) * 1024 + 512);
            }
            #pragma unroll
            for (int n = 0; n < 4; ++n) {
                const char* bp = EpG + (size_t)n * 16384 + c * 2048;
                Bh[n] = *(const half8*)(bp);
                Bl[n] = *(const half8*)(bp + 1024);
            }
            #pragma unroll
            for (int m = 0; m < 4; ++m)
                #pragma unroll
                for (int n = 0; n < 4; ++n) {
                    acc[m][n] = __builtin_amdgcn_mfma_f32_16x16x32_f16(Ah[m], Bh[n], acc[m][n], 0, 0, 0);
                    acc[m][n] = __builtin_amdgcn_mfma_f32_16x16x32_f16(Ah[m], Bl[n], acc[m][n], 0, 0, 0);
                    acc[m][n] = __builtin_amdgcn_mfma_f32_16x16x32_f16(Al[m], Bh[n], acc[m][n], 0, 0, 0);
                }
        }
        // fold group scores into running argmax (cols ascending => first-idx)
        #pragma unroll
        for (int n = 0; n < 4; ++n) {
            int col = colBase + g * 64 + n * 16 + (lane & 15);
            float h2 = he2[col];
            #pragma unroll
            for (int m = 0; m < 4; ++m)
                #pragma unroll
                for (int reg = 0; reg < 4; ++reg) {
                    float s = acc[m][n][reg] - h2;
                    int slot = m * 4 + reg;
                    if (s > best[slot]) { best[slot] = s; bidx[slot] = col; }
                }
        }
    }

    // ---- reduce across the 16 col-lanes of each row ----------------------
    #pragma unroll
    for (int s = 0; s < 16; ++s) {
        float b = best[s]; int bi = bidx[s];
        #pragma unroll
        for (int msk = 1; msk <= 8; msk <<= 1) {
            float ob = __shfl_xor(b, msk, 64);
            int   oi = __shfl_xor(bi, msk, 64);
            if (ob > b || (ob == b && oi < bi)) { b = ob; bi = oi; }
        }
        best[s] = b; bidx[s] = bi;
    }
    if ((lane & 15) == 0) {
        int lhi = lane >> 4;
        #pragma unroll
        for (int s = 0; s < 16; ++s) {
            int row = (s >> 2) * 16 + lhi * 4 + (s & 3);   // block-local row
            sarr[row * 4 + w] = best[s];
            iarr[row * 4 + w] = bidx[s];
        }
    }
    __syncthreads();

    if (t < 64) {
        float bs = sarr[t * 4]; int bi = iarr[t * 4];
        #pragma unroll
        for (int ww = 1; ww < 4; ++ww) {
            float s = sarr[t * 4 + ww]; int i = iarr[t * 4 + ww];
            if (s > bs || (s == bs && i < bi)) { bs = s; bi = i; }
        }
        idxS[t] = bi;
        outi[rowBase + t] = (float)bi;
    }
    __syncthreads();

    // ---- gather: quantize[r][:] = embed[idx[r]][:] -----------------------
    #pragma unroll
    for (int q = 0; q < 16; ++q) {
        int f = t + 256 * q;
        int r = f >> 6, c4 = f & 63;
        int e = idxS[r];
        f32x4 v = *(const f32x4*)(embed + (size_t)e * DIMS + c4 * 4);
        *(f32x4*)(outq + (size_t)(rowBase + r) * DIMS + c4 * 4) = v;
    }
}

extern "C" void kernel_launch(void* const* d_in, const int* in_sizes, int n_in,
                              void* d_out, int out_size, void* d_ws, size_t ws_size,
                              hipStream_t stream) {
    const float* x     = (const float*)d_in[0];
    const float* embed = (const float*)d_in[1];
    float* he2 = (float*)d_ws;                    // 4 KB (+pad to 8 KB)
    short* Ep  = (short*)((char*)d_ws + 8192);    // 2 MB fragment-ordered E
    float* out = (float*)d_out;
    esplit<<<KCB / 4, 256, 0, stream>>>(embed, Ep, he2);
    vq_full<<<NROWS / 64, 256, 0, stream>>>(x, Ep, embed, he2,
                                            out, out + (size_t)NROWS * DIMS);
}

// Round 7
// 100.503 us; speedup vs baseline: 1.4467x; 1.4467x over previous
//
#include <hip/hip_runtime.h>
#include <stdint.h>

#define NROWS 32768
#define DIMS  256
#define KCB   1024
#define BM 128
#define BN 128
#define GY (KCB/BN)   // 8 code-blocks

typedef _Float16 half8   __attribute__((ext_vector_type(8)));
typedef float    f32x4   __attribute__((ext_vector_type(4)));
typedef short    short4v __attribute__((ext_vector_type(4)));
typedef short    short8v __attribute__((ext_vector_type(8)));

// async global->LDS, 16B per lane; LDS dest = uniform base + lane*16
__device__ __forceinline__ void gload_lds16(const void* g, void* l) {
    __builtin_amdgcn_global_load_lds(
        (const __attribute__((address_space(1))) uint32_t*)g,
        (__attribute__((address_space(3))) uint32_t*)l, 16, 0, 0);
}

__device__ __forceinline__ short2 f16split(float v) {
    _Float16 hh = (_Float16)v;
    _Float16 ll = (_Float16)(v - (float)hh);
    return make_short2(__builtin_bit_cast(short, hh),
                       __builtin_bit_cast(short, ll));
}

// ---------------- splitter: X -> fragment-ordered f16 h/l planes ----------
// Xp layout (shorts): frag(G=row-group of 16, c=k-chunk of 32, hl) is 1KB:
//   lane l holds row G*16+(l&15), k = c*32+(l>>4)*8 .. +7
//   short index = G*8192 + c*1024 + hl*512 + l*8
__global__ __launch_bounds__(256) void xsplit(const float* __restrict__ x,
                                              short* __restrict__ Xp) {
    int T = blockIdx.x * 256 + threadIdx.x;
    int l = T & 63, c = (T >> 6) & 7, G = T >> 9;
    int row = G * 16 + (l & 15);
    int kb  = c * 32 + (l >> 4) * 8;
    const f32x4* src = (const f32x4*)(x + (size_t)row * DIMS + kb);
    f32x4 a = src[0], b = src[1];
    short8v h, lo;
    #pragma unroll
    for (int e = 0; e < 4; ++e) { short2 r = f16split(a[e]); h[e] = r.x; lo[e] = r.y; }
    #pragma unroll
    for (int e = 0; e < 4; ++e) { short2 r = f16split(b[e]); h[4 + e] = r.x; lo[4 + e] = r.y; }
    size_t base = (size_t)G * 8192 + c * 1024 + l * 8;
    *(short8v*)(Xp + base)       = h;
    *(short8v*)(Xp + base + 512) = lo;
}

// ---------------- splitter: E (same layout, cols as rows) + he2 -----------
__global__ __launch_bounds__(256) void esplit(const float* __restrict__ embed,
                                              short* __restrict__ Ep,
                                              float* __restrict__ he2) {
    int r = blockIdx.x * 4 + (threadIdx.x >> 6);   // code row 0..1023
    int l = threadIdx.x & 63;
    f32x4 v = ((const f32x4*)(embed + (size_t)r * DIMS))[l];
    float s = v[0]*v[0] + v[1]*v[1] + v[2]*v[2] + v[3]*v[3];
    #pragma unroll
    for (int off = 32; off > 0; off >>= 1) s += __shfl_down(s, off, 64);
    if (l == 0) he2[r] = 0.5f * s;
    int G = r >> 4, cc = l >> 3;
    int fl = (r & 15) + 16 * ((l >> 1) & 3);
    size_t base = (size_t)G * 8192 + cc * 1024 + fl * 8 + (l & 1) * 4;
    short4v h, lo;
    #pragma unroll
    for (int e = 0; e < 4; ++e) { short2 q = f16split(v[e]); h[e] = q.x; lo[e] = q.y; }
    *(short4v*)(Ep + base)       = h;
    *(short4v*)(Ep + base + 512) = lo;
}

// ---------------- main GEMM+argmax: counted-vmcnt double-buffer -----------
#define LDSBUF 32768   // one tile: X frags 16KB + E frags 16KB
__global__ __launch_bounds__(256, 2) void vq_mfma(
    const short* __restrict__ Xp, const short* __restrict__ Ep,
    const float* __restrict__ he2, float2* __restrict__ part)
{
    __shared__ char  lds[2 * LDSBUF];
    __shared__ float sarr[BM * 2];
    __shared__ int   iarr[BM * 2];

    const int t = threadIdx.x, lane = t & 63, w = t >> 6;
    const int wm = w >> 1, wn = w & 1;
    // XCD-swizzle: all 8 code-blocks of a row-panel on one XCD
    const int sid = blockIdx.x;
    const int xcd = sid & 7, j = sid >> 3;
    const int rb = xcd * 32 + (j >> 3), cb = j & 7;
    const int rowBase = rb * BM, colBase = cb * BN;

    // staging: wave w owns fragments f = 8w..8w+7 (f<16: X, else E)
    const char* gbase[8];
    int ldsoff[8];
    #pragma unroll
    for (int p = 0; p < 8; ++p) {
        int f = w * 8 + p;
        ldsoff[p] = f * 1024;
        const char* b;
        if (f < 16) b = (const char*)Xp + ((size_t)(rb * 8 + (f >> 1)) * 16 + (f & 1)) * 1024;
        else        b = (const char*)Ep + ((size_t)(cb * 8 + ((f - 16) >> 1)) * 16 + ((f - 16) & 1)) * 1024;
        gbase[p] = b + lane * 16;
    }

    f32x4 acc[4][4];
    #pragma unroll
    for (int m = 0; m < 4; ++m)
        #pragma unroll
        for (int n = 0; n < 4; ++n) acc[m][n] = (f32x4){0.f, 0.f, 0.f, 0.f};

    // prologue: stage tile 0 -> buf0, tile 1 -> buf1 (16 loads/wave in flight)
    #pragma unroll
    for (int p = 0; p < 8; ++p) gload_lds16(gbase[p], lds + ldsoff[p]);
    #pragma unroll
    for (int p = 0; p < 8; ++p) gload_lds16(gbase[p] + 2048, lds + LDSBUF + ldsoff[p]);

    #pragma unroll
    for (int c = 0; c < 8; ++c) {
        // wait for tile c's (oldest 8) loads; keep tile c+1 in flight
        if (c < 7) asm volatile("s_waitcnt vmcnt(8)" ::: "memory");
        else       asm volatile("s_waitcnt vmcnt(0)" ::: "memory");
        __builtin_amdgcn_sched_barrier(0);
        __builtin_amdgcn_s_barrier();          // all waves: tile c resident

        const char* B = lds + (c & 1) * LDSBUF;
        half8 Ah[4], Al[4], Bh[4], Bl[4];
        #pragma unroll
        for (int m = 0; m < 4; ++m) {
            Ah[m] = *(const half8*)(B + ((wm * 4 + m) * 2) * 1024 + lane * 16);
            Al[m] = *(const half8*)(B + ((wm * 4 + m) * 2 + 1) * 1024 + lane * 16);
        }
        #pragma unroll
        for (int n = 0; n < 4; ++n) {
            Bh[n] = *(const half8*)(B + 16384 + ((wn * 4 + n) * 2) * 1024 + lane * 16);
            Bl[n] = *(const half8*)(B + 16384 + ((wn * 4 + n) * 2 + 1) * 1024 + lane * 16);
        }
        asm volatile("s_waitcnt lgkmcnt(0)" ::: "memory");
        __builtin_amdgcn_sched_barrier(0);     // rule #18: fence after lgkmcnt
        __builtin_amdgcn_s_barrier();          // all waves done reading buf[c&1]

        if (c < 6) {                           // refill freed buffer: tile c+2
            #pragma unroll
            for (int p = 0; p < 8; ++p)
                gload_lds16(gbase[p] + (c + 2) * 2048,
                            lds + (c & 1) * LDSBUF + ldsoff[p]);
        }
        __builtin_amdgcn_sched_barrier(0);     // keep stage-issue before MFMA

        __builtin_amdgcn_s_setprio(1);
        #pragma unroll
        for (int m = 0; m < 4; ++m)
            #pragma unroll
            for (int n = 0; n < 4; ++n) {
                acc[m][n] = __builtin_amdgcn_mfma_f32_16x16x32_f16(Ah[m], Bh[n], acc[m][n], 0, 0, 0);
                acc[m][n] = __builtin_amdgcn_mfma_f32_16x16x32_f16(Ah[m], Bl[n], acc[m][n], 0, 0, 0);
                acc[m][n] = __builtin_amdgcn_mfma_f32_16x16x32_f16(Al[m], Bh[n], acc[m][n], 0, 0, 0);
            }
        __builtin_amdgcn_s_setprio(0);
    }

    // epilogue: score = acc - he2[col]; per-row argmax (verified round 3/5)
    float h2[4];
    const int c15 = lane & 15;
    #pragma unroll
    for (int n = 0; n < 4; ++n) h2[n] = he2[colBase + 64 * wn + 16 * n + c15];
    const int colg0 = colBase + 64 * wn + c15;

    #pragma unroll
    for (int m = 0; m < 4; ++m) {
        #pragma unroll
        for (int reg = 0; reg < 4; ++reg) {
            float b = acc[m][0][reg] - h2[0];
            int bi = colg0;
            #pragma unroll
            for (int n = 1; n < 4; ++n) {
                float s = acc[m][n][reg] - h2[n];
                int c = colg0 + 16 * n;
                if (s > b) { b = s; bi = c; }
            }
            #pragma unroll
            for (int msk = 1; msk <= 8; msk <<= 1) {
                float ob = __shfl_xor(b, msk, 64);
                int   oi = __shfl_xor(bi, msk, 64);
                if (ob > b || (ob == b && oi < bi)) { b = ob; bi = oi; }
            }
            if (c15 == 0) {
                int row = 64 * wm + 16 * m + 4 * (lane >> 4) + reg;
                sarr[row * 2 + wn] = b;
                iarr[row * 2 + wn] = bi;
            }
        }
    }
    __syncthreads();
    if (t < BM) {
        float s0 = sarr[t * 2], s1 = sarr[t * 2 + 1];
        int   i0 = iarr[t * 2], i1 = iarr[t * 2 + 1];
        float bs = s0; int bi = i0;
        if (s1 > bs) { bs = s1; bi = i1; }     // i0 < i1: ties keep i0
        part[(size_t)(rowBase + t) * GY + cb] = make_float2(bs, __int_as_float(bi));
    }
}

// ---------------- combine partials + gather ----------------
__global__ __launch_bounds__(256) void vq_combine(
    const float2* __restrict__ part, const float* __restrict__ embed,
    float* __restrict__ outq, float* __restrict__ outi)
{
    __shared__ int idxS[256];
    const int t = threadIdx.x;
    const int rowBase = blockIdx.x * 256;
    const int row = rowBase + t;

    float2 p0 = part[(size_t)row * GY];
    float bs = p0.x; int bi = __float_as_int(p0.y);
    #pragma unroll
    for (int g = 1; g < GY; ++g) {
        float2 p = part[(size_t)row * GY + g];
        int i = __float_as_int(p.y);
        if (p.x > bs || (p.x == bs && i < bi)) { bs = p.x; bi = i; }
    }
    idxS[t] = bi;
    outi[row] = (float)bi;
    __syncthreads();

    #pragma unroll 4
    for (int q = 0; q < 64; ++q) {
        int f = t + 256 * q;
        int r = f >> 6, c4 = f & 63;
        int e = idxS[r];
        f32x4 v = *(const f32x4*)(embed + (size_t)e * DIMS + c4 * 4);
        *(f32x4*)(outq + (size_t)(rowBase + r) * DIMS + c4 * 4) = v;
    }
}

extern "C" void kernel_launch(void* const* d_in, const int* in_sizes, int n_in,
                              void* d_out, int out_size, void* d_ws, size_t ws_size,
                              hipStream_t stream) {
    const float* x     = (const float*)d_in[0];
    const float* embed = (const float*)d_in[1];
    float*  he2  = (float*)d_ws;                          // 4 KB (+pad)
    float2* part = (float2*)((char*)d_ws + 8192);         // 2 MB
    short*  Xp   = (short*)((char*)d_ws + 8192 + 2097152);        // 32 MB
    short*  Ep   = (short*)((char*)d_ws + 8192 + 2097152 + 33554432); // 1 MB
    float*  out  = (float*)d_out;

    xsplit<<<4096, 256, 0, stream>>>(x, Xp);
    esplit<<<256, 256, 0, stream>>>(embed, Ep, he2);
    vq_mfma<<<(NROWS / BM) * GY, 256, 0, stream>>>(Xp, Ep, he2, part);
    vq_combine<<<NROWS / 256, 256, 0, stream>>>(part, embed, out, out + (size_t)NROWS * DIMS);
}

// Round 8
// 92.036 us; speedup vs baseline: 1.5797x; 1.0920x over previous
//
#include <hip/hip_runtime.h>
#include <stdint.h>

#define NROWS 32768
#define DIMS  256
#define KCB   1024
#define BM 128
#define BN 128
#define GY (KCB/BN)   // 8 code-blocks

typedef _Float16 half8   __attribute__((ext_vector_type(8)));
typedef float    f32x4   __attribute__((ext_vector_type(4)));
typedef short    short4v __attribute__((ext_vector_type(4)));
typedef short    short8v __attribute__((ext_vector_type(8)));

// async global->LDS, 16B per lane; LDS dest = wave-uniform base + lane*16
__device__ __forceinline__ void gload_lds16(const void* g, void* l) {
    __builtin_amdgcn_global_load_lds(
        (const __attribute__((address_space(1))) uint32_t*)g,
        (__attribute__((address_space(3))) uint32_t*)l, 16, 0, 0);
}

__device__ __forceinline__ short2 f16split(float v) {
    _Float16 hh = (_Float16)v;
    _Float16 ll = (_Float16)(v - (float)hh);
    return make_short2(__builtin_bit_cast(short, hh),
                       __builtin_bit_cast(short, ll));
}

// ---------------- splitter: X -> fragment-ordered f16 h/l planes ----------
// Xp layout: frag(G=row-group of 16, c=k-chunk of 32, hl) is 1KB:
//   lane l holds row G*16+(l&15), k = c*32+(l>>4)*8 .. +7
//   byte addr = G*16384 + c*2048 + hl*1024 + l*16
__global__ __launch_bounds__(256) void xsplit(const float* __restrict__ x,
                                              short* __restrict__ Xp) {
    int T = blockIdx.x * 256 + threadIdx.x;
    int l = T & 63, c = (T >> 6) & 7, G = T >> 9;
    int row = G * 16 + (l & 15);
    int kb  = c * 32 + (l >> 4) * 8;
    const f32x4* src = (const f32x4*)(x + (size_t)row * DIMS + kb);
    f32x4 a = src[0], b = src[1];
    short8v h, lo;
    #pragma unroll
    for (int e = 0; e < 4; ++e) { short2 r = f16split(a[e]); h[e] = r.x; lo[e] = r.y; }
    #pragma unroll
    for (int e = 0; e < 4; ++e) { short2 r = f16split(b[e]); h[4 + e] = r.x; lo[4 + e] = r.y; }
    size_t base = (size_t)G * 8192 + c * 1024 + l * 8;
    *(short8v*)(Xp + base)       = h;
    *(short8v*)(Xp + base + 512) = lo;
}

// ---------------- splitter: E (same layout, cols as rows) + he2 -----------
__global__ __launch_bounds__(256) void esplit(const float* __restrict__ embed,
                                              short* __restrict__ Ep,
                                              float* __restrict__ he2) {
    int r = blockIdx.x * 4 + (threadIdx.x >> 6);   // code row 0..1023
    int l = threadIdx.x & 63;
    f32x4 v = ((const f32x4*)(embed + (size_t)r * DIMS))[l];
    float s = v[0]*v[0] + v[1]*v[1] + v[2]*v[2] + v[3]*v[3];
    #pragma unroll
    for (int off = 32; off > 0; off >>= 1) s += __shfl_down(s, off, 64);
    if (l == 0) he2[r] = 0.5f * s;
    int G = r >> 4, cc = l >> 3;
    int fl = (r & 15) + 16 * ((l >> 1) & 3);
    size_t base = (size_t)G * 8192 + cc * 1024 + fl * 8 + (l & 1) * 4;
    short4v h, lo;
    #pragma unroll
    for (int e = 0; e < 4; ++e) { short2 q = f16split(v[e]); h[e] = q.x; lo[e] = q.y; }
    *(short4v*)(Ep + base)       = h;
    *(short4v*)(Ep + base + 512) = lo;
}

// ------- main GEMM+argmax: single 32KB tile, 3 sub-phases, 4 blocks/CU ----
// LDS quarters (8KB each): Q0=Ah @0, Q1=Bh @8192, Q2=Al @16384, Q3=Bl @24576.
// Wave w stages quarter w for the next chunk (8 x gload_lds16, stride 16KB).
__global__ __launch_bounds__(256, 3) void vq_mfma(
    const short* __restrict__ Xp, const short* __restrict__ Ep,
    const float* __restrict__ he2, float2* __restrict__ part)
{
    __shared__ char  lds[32768];
    __shared__ float sarr[BM * 2];
    __shared__ int   iarr[BM * 2];

    const int t = threadIdx.x, lane = t & 63, w = t >> 6;
    const int wm = w >> 1, wn = w & 1;
    // XCD-swizzle: all 8 code-blocks of a row-panel on one XCD
    const int sid = blockIdx.x;
    const int xcd = sid & 7, j = sid >> 3;
    const int rb = xcd * 32 + (j >> 3), cb = j & 7;
    const int rowBase = rb * BM, colBase = cb * BN;

    // staging source for wave w's quarter (h/l plane select = w>>1)
    const char* gsrc = (w & 1) ? ((const char*)Ep + (size_t)(cb * 8) * 16384)
                               : ((const char*)Xp + (size_t)(rb * 8) * 16384);
    gsrc += (w >> 1) * 1024 + lane * 16;
    char* ldsq = lds + w * 8192;

    // per-wave read bases (lane-linear, conflict-free b128)
    const char* A0 = lds +         (wm * 4) * 1024 + lane * 16;  // Ah
    const char* B0 = lds +  8192 + (wn * 4) * 1024 + lane * 16;  // Bh
    const char* A1 = lds + 16384 + (wm * 4) * 1024 + lane * 16;  // Al
    const char* B1 = lds + 24576 + (wn * 4) * 1024 + lane * 16;  // Bl

    f32x4 acc[4][4];
    #pragma unroll
    for (int m = 0; m < 4; ++m)
        #pragma unroll
        for (int n = 0; n < 4; ++n) acc[m][n] = (f32x4){0.f, 0.f, 0.f, 0.f};

    // prologue: stage chunk 0
    #pragma unroll
    for (int g = 0; g < 8; ++g)
        gload_lds16(gsrc + (size_t)g * 16384, ldsq + g * 1024);

    #pragma unroll
    for (int c = 0; c < 8; ++c) {
        asm volatile("s_waitcnt vmcnt(0)" ::: "memory");  // my quarter staged
        __builtin_amdgcn_sched_barrier(0);
        __builtin_amdgcn_s_barrier();                     // all quarters resident

        half8 Ah[4], Bh[4];
        #pragma unroll
        for (int m = 0; m < 4; ++m) Ah[m] = *(const half8*)(A0 + m * 1024);
        #pragma unroll
        for (int n = 0; n < 4; ++n) Bh[n] = *(const half8*)(B0 + n * 1024);
        asm volatile("s_waitcnt lgkmcnt(0)" ::: "memory");
        __builtin_amdgcn_sched_barrier(0);
        __builtin_amdgcn_s_setprio(1);
        #pragma unroll
        for (int m = 0; m < 4; ++m)
            #pragma unroll
            for (int n = 0; n < 4; ++n)
                acc[m][n] = __builtin_amdgcn_mfma_f32_16x16x32_f16(Ah[m], Bh[n], acc[m][n], 0, 0, 0);
        __builtin_amdgcn_s_setprio(0);

        {
            half8 Al[4];
            #pragma unroll
            for (int m = 0; m < 4; ++m) Al[m] = *(const half8*)(A1 + m * 1024);
            asm volatile("s_waitcnt lgkmcnt(0)" ::: "memory");
            __builtin_amdgcn_sched_barrier(0);
            __builtin_amdgcn_s_setprio(1);
            #pragma unroll
            for (int m = 0; m < 4; ++m)
                #pragma unroll
                for (int n = 0; n < 4; ++n)
                    acc[m][n] = __builtin_amdgcn_mfma_f32_16x16x32_f16(Al[m], Bh[n], acc[m][n], 0, 0, 0);
            __builtin_amdgcn_s_setprio(0);
        }

        half8 Bl[4];
        #pragma unroll
        for (int n = 0; n < 4; ++n) Bl[n] = *(const half8*)(B1 + n * 1024);
        asm volatile("s_waitcnt lgkmcnt(0)" ::: "memory");
        __builtin_amdgcn_sched_barrier(0);
        __builtin_amdgcn_s_barrier();                     // all waves done reading

        if (c < 7) {                                      // refill in place
            #pragma unroll
            for (int g = 0; g < 8; ++g)
                gload_lds16(gsrc + (size_t)g * 16384 + (c + 1) * 2048,
                            ldsq + g * 1024);
        }
        __builtin_amdgcn_sched_barrier(0);                // keep stage before MFMA

        __builtin_amdgcn_s_setprio(1);
        #pragma unroll
        for (int m = 0; m < 4; ++m)
            #pragma unroll
            for (int n = 0; n < 4; ++n)
                acc[m][n] = __builtin_amdgcn_mfma_f32_16x16x32_f16(Ah[m], Bl[n], acc[m][n], 0, 0, 0);
        __builtin_amdgcn_s_setprio(0);
    }

    // epilogue: score = acc - he2[col]; per-row argmax (verified round 3/5/7)
    float h2[4];
    const int c15 = lane & 15;
    #pragma unroll
    for (int n = 0; n < 4; ++n) h2[n] = he2[colBase + 64 * wn + 16 * n + c15];
    const int colg0 = colBase + 64 * wn + c15;

    #pragma unroll
    for (int m = 0; m < 4; ++m) {
        #pragma unroll
        for (int reg = 0; reg < 4; ++reg) {
            float b = acc[m][0][reg] - h2[0];
            int bi = colg0;
            #pragma unroll
            for (int n = 1; n < 4; ++n) {
                float s = acc[m][n][reg] - h2[n];
                int c = colg0 + 16 * n;
                if (s > b) { b = s; bi = c; }
            }
            #pragma unroll
            for (int msk = 1; msk <= 8; msk <<= 1) {
                float ob = __shfl_xor(b, msk, 64);
                int   oi = __shfl_xor(bi, msk, 64);
                if (ob > b || (ob == b && oi < bi)) { b = ob; bi = oi; }
            }
            if (c15 == 0) {
                int row = 64 * wm + 16 * m + 4 * (lane >> 4) + reg;
                sarr[row * 2 + wn] = b;
                iarr[row * 2 + wn] = bi;
            }
        }
    }
    __syncthreads();
    if (t < BM) {
        float s0 = sarr[t * 2], s1 = sarr[t * 2 + 1];
        int   i0 = iarr[t * 2], i1 = iarr[t * 2 + 1];
        float bs = s0; int bi = i0;
        if (s1 > bs) { bs = s1; bi = i1; }     // i0 < i1: ties keep i0
        part[(size_t)(rowBase + t) * GY + cb] = make_float2(bs, __int_as_float(bi));
    }
}

// ---------------- combine partials + gather ----------------
__global__ __launch_bounds__(256) void vq_combine(
    const float2* __restrict__ part, const float* __restrict__ embed,
    float* __restrict__ outq, float* __restrict__ outi)
{
    __shared__ int idxS[256];
    const int t = threadIdx.x;
    const int rowBase = blockIdx.x * 256;
    const int row = rowBase + t;

    float2 p0 = part[(size_t)row * GY];
    float bs = p0.x; int bi = __float_as_int(p0.y);
    #pragma unroll
    for (int g = 1; g < GY; ++g) {
        float2 p = part[(size_t)row * GY + g];
        int i = __float_as_int(p.y);
        if (p.x > bs || (p.x == bs && i < bi)) { bs = p.x; bi = i; }
    }
    idxS[t] = bi;
    outi[row] = (float)bi;
    __syncthreads();

    #pragma unroll 4
    for (int q = 0; q < 64; ++q) {
        int f = t + 256 * q;
        int r = f >> 6, c4 = f & 63;
        int e = idxS[r];
        f32x4 v = *(const f32x4*)(embed + (size_t)e * DIMS + c4 * 4);
        *(f32x4*)(outq + (size_t)(rowBase + r) * DIMS + c4 * 4) = v;
    }
}

extern "C" void kernel_launch(void* const* d_in, const int* in_sizes, int n_in,
                              void* d_out, int out_size, void* d_ws, size_t ws_size,
                              hipStream_t stream) {
    const float* x     = (const float*)d_in[0];
    const float* embed = (const float*)d_in[1];
    float*  he2  = (float*)d_ws;                          // 4 KB (+pad)
    float2* part = (float2*)((char*)d_ws + 8192);         // 2 MB
    short*  Xp   = (short*)((char*)d_ws + 8192 + 2097152);        // 32 MB
    short*  Ep   = (short*)((char*)d_ws + 8192 + 2097152 + 33554432); // 1 MB
    float*  out  = (float*)d_out;

    xsplit<<<4096, 256, 0, stream>>>(x, Xp);
    esplit<<<256, 256, 0, stream>>>(embed, Ep, he2);
    vq_mfma<<<(NROWS / BM) * GY, 256, 0, stream>>>(Xp, Ep, he2, part);
    vq_combine<<<NROWS / 256, 256, 0, stream>>>(part, embed, out, out + (size_t)NROWS * DIMS);
}